// Round 1
// baseline (830.536 us; speedup 1.0000x reference)
//
#include <hip/hip_runtime.h>

#define BB 256
#define TT 1024
#define HH 128
#define CC 2

__global__ __launch_bounds__(256, 1) void rnn_kernel(
    const float* __restrict__ x, const float* __restrict__ W_ih,
    const float* __restrict__ W_hh, const float* __restrict__ b_ih,
    const float* __restrict__ b_hh, const float* __restrict__ W_fc,
    const float* __restrict__ b_fc, float* __restrict__ out)
{
    const int b    = blockIdx.x;
    const int tid  = threadIdx.x;
    const int h    = tid >> 1;   // 0..127
    const int ks   = tid & 1;    // which K-half of the dot product
    const int lane = tid & 63;
    const int wave = tid >> 6;

    __shared__ float xs[TT];            // this row's input sequence
    __shared__ float hbuf[2][HH];       // double-buffered hidden state
    __shared__ float red[2][4][2];      // logits cross-wave combine (double-buffered)

    // preload x row (1024 floats = 256 x float4, coalesced)
    {
        const float4* xr = (const float4*)(x + (size_t)b * TT);
        ((float4*)xs)[tid] = xr[tid];
    }
    if (tid < HH) hbuf[0][tid] = 0.f;   // h0 = 0

    // per-thread constants
    const float wih  = W_ih[h];                     // INPUT_DIM = 1
    const float bias = b_ih[h] + b_hh[h];
    const float wfc  = W_fc[ks * HH + h];           // this lane's class = ks
    const float bfc  = (tid < CC) ? b_fc[tid] : 0.f;

    // W_hh half-row in registers: W_hh[h][ks*64 .. ks*64+63]  (64 VGPRs)
    float4 wr[16];
    {
        const float4* wrow = (const float4*)(W_hh + h * HH + ks * 64);
        #pragma unroll
        for (int j = 0; j < 16; ++j) wr[j] = wrow[j];
    }

    __syncthreads();

    float* o = out + (size_t)b * TT * CC;

    for (int t = 0; t < TT; ++t) {
        // partial dot over this thread's K-half; 4 accumulators break dep chain
        const float4* hb = (const float4*)(hbuf[t & 1] + ks * 64);
        float a0 = 0.f, a1 = 0.f, a2 = 0.f, a3 = 0.f;
        #pragma unroll
        for (int j = 0; j < 16; ++j) {
            float4 v = hb[j];
            a0 = fmaf(wr[j].x, v.x, a0);
            a1 = fmaf(wr[j].y, v.y, a1);
            a2 = fmaf(wr[j].z, v.z, a2);
            a3 = fmaf(wr[j].w, v.w, a3);
        }
        float acc = (a0 + a1) + (a2 + a3);
        acc += __shfl_xor(acc, 1);                 // combine the two K-halves (in-wave)

        float u  = fmaf(xs[t], wih, bias) + acc;
        float hn = tanhf(u);

        if (ks == 0) hbuf[(t + 1) & 1][h] = hn;    // write next h (other buffer)

        // logits: lane parity = class; xor-tree over strides 2..32 sums over h in wave
        float p = wfc * hn;
        p += __shfl_xor(p, 2);
        p += __shfl_xor(p, 4);
        p += __shfl_xor(p, 8);
        p += __shfl_xor(p, 16);
        p += __shfl_xor(p, 32);
        if (lane < CC) red[t & 1][wave][lane] = p;

        __syncthreads();                            // the single per-step barrier

        if (tid < CC) {
            float s = red[t & 1][0][tid] + red[t & 1][1][tid]
                    + red[t & 1][2][tid] + red[t & 1][3][tid] + bfc;
            o[t * CC + tid] = s;
        }
    }
}

extern "C" void kernel_launch(void* const* d_in, const int* in_sizes, int n_in,
                              void* d_out, int out_size, void* d_ws, size_t ws_size,
                              hipStream_t stream) {
    const float* x    = (const float*)d_in[0];
    const float* W_ih = (const float*)d_in[1];
    const float* W_hh = (const float*)d_in[2];
    const float* b_ih = (const float*)d_in[3];
    const float* b_hh = (const float*)d_in[4];
    const float* W_fc = (const float*)d_in[5];
    const float* b_fc = (const float*)d_in[6];
    float* out = (float*)d_out;

    rnn_kernel<<<BB, 256, 0, stream>>>(x, W_ih, W_hh, b_ih, b_hh, W_fc, b_fc, out);
}

// Round 2
// 705.629 us; speedup vs baseline: 1.1770x; 1.1770x over previous
//
#include <hip/hip_runtime.h>

#define BB 256
#define TT 1024
#define HH 128
#define CC 2

__global__ __launch_bounds__(256, 1) void rnn_kernel(
    const float* __restrict__ x, const float* __restrict__ W_ih,
    const float* __restrict__ W_hh, const float* __restrict__ b_ih,
    const float* __restrict__ b_hh, const float* __restrict__ W_fc,
    const float* __restrict__ b_fc, float* __restrict__ out)
{
    const int b    = blockIdx.x;
    const int tid  = threadIdx.x;
    const int lane = tid & 63;
    const int wv   = tid >> 6;                 // 0..3
    const int ks   = wv >> 1;                  // waves 0,1 -> K-half 0; waves 2,3 -> K-half 1
    const int row  = ((wv & 1) << 6) + lane;   // output row 0..127 (wave-contiguous)

    __shared__ float xs[TT];         // input sequence for this batch row
    __shared__ float hbuf[2][HH];    // double-buffered hidden state
    __shared__ float pbuf[HH];       // ks=1 partials

    // preload x row (coalesced float4)
    {
        const float4* xr = (const float4*)(x + (size_t)b * TT);
        ((float4*)xs)[tid] = xr[tid];
    }
    if (tid < HH) hbuf[0][tid] = 0.f;

    // per-thread constants
    const float wih  = W_ih[row];               // INPUT_DIM = 1
    const float bias = b_ih[row] + b_hh[row];
    const int   cls  = wv & 1;                  // waves 2,3: class 0 / 1
    const float wf0  = W_fc[cls * HH + lane];
    const float wf1  = W_fc[cls * HH + 64 + lane];
    const float bfc  = b_fc[cls];

    // W_hh half-row in registers: W_hh[row][ks*64 .. ks*64+63] (64 VGPRs)
    float4 wr[16];
    {
        const float4* wrow = (const float4*)(W_hh + row * HH + ks * 64);
        #pragma unroll
        for (int j = 0; j < 16; ++j) wr[j] = wrow[j];
    }

    __syncthreads();

    float* o = out + (size_t)b * TT * CC;
    int cur = 0;

    for (int t = 0; t < TT; ++t) {
        // ---- phase 1: every wave does its K-half partial dot.
        // All 64 lanes of a wave read the SAME hbuf addresses -> pure broadcast,
        // zero bank conflicts.
        const float4* hb = (const float4*)(hbuf[cur] + ks * 64);
        float a0 = 0.f, a1 = 0.f, a2 = 0.f, a3 = 0.f;
        #pragma unroll
        for (int j = 0; j < 16; ++j) {
            float4 v = hb[j];
            a0 = fmaf(wr[j].x, v.x, a0);
            a1 = fmaf(wr[j].y, v.y, a1);
            a2 = fmaf(wr[j].z, v.z, a2);
            a3 = fmaf(wr[j].w, v.w, a3);
        }
        float p = (a0 + a1) + (a2 + a3);

        if (tid >= 128) pbuf[row] = p;   // ks=1 partials -> LDS (2-way alias, free)
        __syncthreads();

        const int nxt = cur ^ 1;
        if (tid < 128) {
            // ---- phase 2a (waves 0,1): combine halves, tanh, write h_{t}
            float acc = p + pbuf[row];
            float u   = fmaf(xs[t], wih, bias) + acc;
            float hn  = tanhf(u);
            hbuf[nxt][row] = hn;
        } else if (t > 0) {
            // ---- phase 2b (waves 2,3): logits for step t-1 from h_{t-1}=hbuf[cur]
            float q = fmaf(wf0, hbuf[cur][lane], wf1 * hbuf[cur][64 + lane]);
            q += __shfl_xor(q, 1);
            q += __shfl_xor(q, 2);
            q += __shfl_xor(q, 4);
            q += __shfl_xor(q, 8);
            q += __shfl_xor(q, 16);
            q += __shfl_xor(q, 32);
            if (lane == 0) o[(t - 1) * CC + cls] = q + bfc;
        }
        __syncthreads();
        cur = nxt;
    }

    // epilogue: logits for the final step from hbuf[cur]
    if (tid >= 128) {
        float q = fmaf(wf0, hbuf[cur][lane], wf1 * hbuf[cur][64 + lane]);
        q += __shfl_xor(q, 1);
        q += __shfl_xor(q, 2);
        q += __shfl_xor(q, 4);
        q += __shfl_xor(q, 8);
        q += __shfl_xor(q, 16);
        q += __shfl_xor(q, 32);
        if (lane == 0) o[(TT - 1) * CC + cls] = q + bfc;
    }
}

extern "C" void kernel_launch(void* const* d_in, const int* in_sizes, int n_in,
                              void* d_out, int out_size, void* d_ws, size_t ws_size,
                              hipStream_t stream) {
    const float* x    = (const float*)d_in[0];
    const float* W_ih = (const float*)d_in[1];
    const float* W_hh = (const float*)d_in[2];
    const float* b_ih = (const float*)d_in[3];
    const float* b_hh = (const float*)d_in[4];
    const float* W_fc = (const float*)d_in[5];
    const float* b_fc = (const float*)d_in[6];
    float* out = (float*)d_out;

    rnn_kernel<<<BB, 256, 0, stream>>>(x, W_ih, W_hh, b_ih, b_hh, W_fc, b_fc, out);
}